// Round 1
// baseline (1021.537 us; speedup 1.0000x reference)
//
#include <hip/hip_runtime.h>

#define B_ 64
#define L_ 256
#define E_ 128
#define C_ 16
#define K_ 5
#define NL_ 4
#define STEP_ 0.1f

// ---------------- embedding gather: h0[b,e,l] = emb[aa[b,l], e] ----------------
__global__ void k_embed(const int* __restrict__ aa, const float* __restrict__ emb,
                        float* __restrict__ h0) {
  int idx = blockIdx.x * 256 + threadIdx.x;
  if (idx >= B_ * E_ * L_) return;
  int l = idx & (L_ - 1);
  int e = (idx >> 8) & (E_ - 1);
  int b = idx >> 15;
  h0[idx] = emb[aa[b * L_ + l] * E_ + e];
}

// ---------------- one conv layer: hout = tanh(hin + conv(hin,w) + bias) ----------------
// block = (l-tile of 32, b), 256 threads: o = tid>>1 (0..127), lh = tid&1 (16 l's each)
__global__ __launch_bounds__(256) void k_conv(const float* __restrict__ hin,
                                              const float* __restrict__ w,
                                              const float* __restrict__ bias,
                                              float* __restrict__ hout) {
  __shared__ __align__(16) float hs[E_][40];  // 36 used, stride 40 for 16B alignment
  const int b = blockIdx.y;
  const int lb = blockIdx.x * 32;
  const int t = threadIdx.x;

  // stage h[b, :, lb-2 .. lb+33] with zero padding (SAME, pad=2)
  for (int s = t; s < E_ * 36; s += 256) {
    int i = s / 36, xw = s - i * 36;
    int lp = lb + xw - 2;
    hs[i][xw] = (lp >= 0 && lp < L_) ? hin[(b * E_ + i) * L_ + lp] : 0.0f;
  }
  __syncthreads();

  const int o = t >> 1, lh = t & 1;
  const int l0 = lh * 16;
  float acc[16];
#pragma unroll
  for (int j = 0; j < 16; ++j) acc[j] = 0.0f;

  const float* wrow = w + o * (E_ * K_);
  for (int i = 0; i < E_; ++i) {
    const float wv0 = wrow[i * 5 + 0];
    const float wv1 = wrow[i * 5 + 1];
    const float wv2 = wrow[i * 5 + 2];
    const float wv3 = wrow[i * 5 + 3];
    const float wv4 = wrow[i * 5 + 4];
    const float4* hp = reinterpret_cast<const float4*>(&hs[i][l0]);
    float4 q0 = hp[0], q1 = hp[1], q2 = hp[2], q3 = hp[3], q4 = hp[4];
    float hw[20] = {q0.x, q0.y, q0.z, q0.w, q1.x, q1.y, q1.z, q1.w,
                    q2.x, q2.y, q2.z, q2.w, q3.x, q3.y, q3.z, q3.w,
                    q4.x, q4.y, q4.z, q4.w};
#pragma unroll
    for (int j = 0; j < 16; ++j) {
      acc[j] = fmaf(wv0, hw[j], acc[j]);
      acc[j] = fmaf(wv1, hw[j + 1], acc[j]);
      acc[j] = fmaf(wv2, hw[j + 2], acc[j]);
      acc[j] = fmaf(wv3, hw[j + 3], acc[j]);
      acc[j] = fmaf(wv4, hw[j + 4], acc[j]);
    }
  }
  const float bo = bias[o];
#pragma unroll
  for (int j = 0; j < 16; ++j) {
    float res = hs[o][l0 + j + 2];
    hout[(b * E_ + o) * L_ + lb + l0 + j] = tanhf(acc[j] + res + bo);
  }
}

// ---------------- transpose (B,E,L) -> (B,L,E) ----------------
__global__ void k_transpose(const float* __restrict__ h, float* __restrict__ x) {
  __shared__ float tl[32][33];
  const int b = blockIdx.z;
  const int lt = blockIdx.x * 32;
  const int et = blockIdx.y * 32;
  const int tx = threadIdx.x & 31, ty = threadIdx.x >> 5;  // ty 0..7
  for (int r = ty; r < 32; r += 8)
    tl[r][tx] = h[(b * E_ + et + r) * L_ + lt + tx];
  __syncthreads();
  for (int r = ty; r < 32; r += 8)
    x[(b * L_ + lt + r) * E_ + et + tx] = tl[tx][r];
}

// ---------------- fused: x2-proj + scores + softmax(C) + pairwise accum + vd ----------------
// grid = B * (L/8); block 512.  Per block: b, a-tile of 8.
__global__ __launch_bounds__(512, 2) void k_fused(
    const float* __restrict__ x,    // (B,L,E)
    const float* __restrict__ bb,   // (B,L,3)
    const float* __restrict__ t1w,  // (2048,128)
    const float* __restrict__ t1b,  // (2048)
    const float* __restrict__ t2w,  // (48,3)
    const float* __restrict__ t2b,  // (48)
    float* __restrict__ nbb)        // (B,L,3)
{
  __shared__ __align__(16) float xa[8][E_];      //  4 KB
  __shared__ __align__(16) float x2t[8][2052];   // 65.7 KB (stride 2052: a-rows hit distinct banks)
  __shared__ __align__(16) float xd[128][132];   // 67.6 KB (pad 132: dg-rows spread banks)
  __shared__ __align__(16) float bbs[L_ * 3];    //  3 KB
  __shared__ __align__(16) float red[8][64];     //  2 KB   (total ~139 KB < 160 KB)

  const int t = threadIdx.x;
  const int b = blockIdx.x >> 5;
  const int a0 = (blockIdx.x & 31) << 3;

  for (int s = t; s < L_ * 3; s += 512) bbs[s] = bb[b * (L_ * 3) + s];
  for (int s = t; s < 8 * E_; s += 512) {
    int ap = s >> 7, e = s & (E_ - 1);
    xa[ap][e] = x[(b * L_ + a0 + ap) * E_ + e];
  }
  __syncthreads();

  // ---- phase 1: x2t[ap][e*16+c] = dot(x[b,a0+ap,:], t1w[e*16+c,:]) + t1b ----
  const float4* xa4 = reinterpret_cast<const float4*>(&xa[0][0]);
#pragma unroll
  for (int j = 0; j < 2; ++j) {
    const int ecA = t + 1024 * j;
    const int ecB = ecA + 512;
    const float4* wA = reinterpret_cast<const float4*>(t1w + ecA * E_);
    const float4* wB = reinterpret_cast<const float4*>(t1w + ecB * E_);
    float accA[8], accB[8];
#pragma unroll
    for (int ap = 0; ap < 8; ++ap) { accA[ap] = 0.f; accB[ap] = 0.f; }
    for (int e4 = 0; e4 < 32; ++e4) {
      float4 wa = wA[e4];
      float4 wb = wB[e4];
#pragma unroll
      for (int ap = 0; ap < 8; ++ap) {
        float4 xv = xa4[ap * 32 + e4];
        accA[ap] += wa.x * xv.x + wa.y * xv.y + wa.z * xv.z + wa.w * xv.w;
        accB[ap] += wb.x * xv.x + wb.y * xv.y + wb.z * xv.z + wb.w * xv.w;
      }
    }
    const float bA = t1b[ecA], bB = t1b[ecB];
#pragma unroll
    for (int ap = 0; ap < 8; ++ap) {
      x2t[ap][ecA] = accA[ap] + bA;
      x2t[ap][ecB] = accB[ap] + bB;
    }
  }

  // ---- phase 2: scores over d, softmax over C (in-register), accumulate s / smsum ----
  float s_s[C_][3], s_sum[C_];
#pragma unroll
  for (int c = 0; c < C_; ++c) {
    s_s[c][0] = 0.f; s_s[c][1] = 0.f; s_s[c][2] = 0.f; s_sum[c] = 0.f;
  }

  const int a = t & 7;
  const int dg = t >> 3;  // 0..63
  const int aglob = a0 + a;
  const float bax = bbs[aglob * 3 + 0];
  const float bay = bbs[aglob * 3 + 1];
  const float baz = bbs[aglob * 3 + 2];
  const float4* x2t4a = reinterpret_cast<const float4*>(&x2t[a][0]);

  __syncthreads();

  for (int chunk = 0; chunk < 2; ++chunk) {
    const int d0 = chunk * 128;
    for (int s = t; s < 128 * E_; s += 512) {
      int dd = s >> 7, e = s & (E_ - 1);
      xd[dd][e] = x[(b * L_ + d0 + dd) * E_ + e];
    }
    __syncthreads();

    float acc[2][C_];
#pragma unroll
    for (int c = 0; c < C_; ++c) { acc[0][c] = 0.f; acc[1][c] = 0.f; }

    const float4* xd40 = reinterpret_cast<const float4*>(&xd[2 * dg][0]);
    const float4* xd41 = reinterpret_cast<const float4*>(&xd[2 * dg + 1][0]);

    for (int e4 = 0; e4 < 32; ++e4) {
      float4 q0 = xd40[e4];
      float4 q1 = xd41[e4];
      float xe0[4] = {q0.x, q0.y, q0.z, q0.w};
      float xe1[4] = {q1.x, q1.y, q1.z, q1.w};
#pragma unroll
      for (int r = 0; r < 4; ++r) {
        float4 w0 = x2t4a[(e4 * 4 + r) * 4 + 0];
        float4 w1 = x2t4a[(e4 * 4 + r) * 4 + 1];
        float4 w2 = x2t4a[(e4 * 4 + r) * 4 + 2];
        float4 w3 = x2t4a[(e4 * 4 + r) * 4 + 3];
        float wv[16] = {w0.x, w0.y, w0.z, w0.w, w1.x, w1.y, w1.z, w1.w,
                        w2.x, w2.y, w2.z, w2.w, w3.x, w3.y, w3.z, w3.w};
        const float xv0 = xe0[r], xv1 = xe1[r];
#pragma unroll
        for (int c = 0; c < C_; ++c) {
          acc[0][c] = fmaf(xv0, wv[c], acc[0][c]);
          acc[1][c] = fmaf(xv1, wv[c], acc[1][c]);
        }
      }
    }

#pragma unroll
    for (int dd = 0; dd < 2; ++dd) {
      const int dglob = d0 + 2 * dg + dd;
      float mx = acc[dd][0];
#pragma unroll
      for (int c = 1; c < C_; ++c) mx = fmaxf(mx, acc[dd][c]);
      float p[C_];
      float S = 0.f;
#pragma unroll
      for (int c = 0; c < C_; ++c) { p[c] = __expf(acc[dd][c] - mx); S += p[c]; }
      const float inv = 1.f / S;
      const float dx = bax - bbs[dglob * 3 + 0];
      const float dy = bay - bbs[dglob * 3 + 1];
      const float dz = baz - bbs[dglob * 3 + 2];
#pragma unroll
      for (int c = 0; c < C_; ++c) {
        const float smv = p[c] * inv;
        s_sum[c] += smv;
        s_s[c][0] = fmaf(smv, dx, s_s[c][0]);
        s_s[c][1] = fmaf(smv, dy, s_s[c][1]);
        s_s[c][2] = fmaf(smv, dz, s_s[c][2]);
      }
    }
    __syncthreads();  // xd reads done before restage / alias
  }

  // ---- phase 3: reduce 64 dg-threads per a (shfl within wave, LDS across waves) ----
  float* part2 = &xd[0][0];  // alias (xd dead): [8 waves][8 a][64 q]
  const int lane = t & 63;
  const int wv = t >> 6;
#pragma unroll
  for (int q = 0; q < 64; ++q) {
    float v = (q < 48) ? s_s[q / 3][q % 3] : s_sum[q - 48];
    v += __shfl_xor(v, 8);
    v += __shfl_xor(v, 16);
    v += __shfl_xor(v, 32);
    if (lane < 8) part2[(wv * 8 + lane) * 64 + q] = v;
  }
  __syncthreads();
  {
    const int a2 = t >> 6, q = t & 63;
    float v = 0.f;
#pragma unroll
    for (int w8 = 0; w8 < 8; ++w8) v += part2[(w8 * 8 + a2) * 64 + q];
    red[a2][q] = v;
  }
  __syncthreads();

  // ---- phase 4: vd[a,k] and new_bb ----
  if (t < 24) {
    const int a2 = t / 3, k = t % 3;
    float vd = 0.f;
#pragma unroll
    for (int c = 0; c < C_; ++c) {
      const float* w2 = t2w + (k * C_ + c) * 3;
      vd += w2[0] * red[a2][c * 3 + 0] + w2[1] * red[a2][c * 3 + 1] +
            w2[2] * red[a2][c * 3 + 2];
      vd += t2b[k * C_ + c] * red[a2][48 + c];
    }
    nbb[(b * L_ + a0 + a2) * 3 + k] = bbs[(a0 + a2) * 3 + k] + STEP_ * vd;
  }
}

// ---------------- mse over frames ----------------
__global__ void k_mse(const float* __restrict__ nbb, const float* __restrict__ bb,
                      float* __restrict__ out) {
  const int b = blockIdx.x;  // 0..B-2
  const int t = threadIdx.x; // 256 == L
  const float* pn = nbb + ((b + 1) * L_ + t) * 3;
  const float* pb = bb + (b * L_ + t) * 3;
  const float dx = pn[0] - pb[0];
  const float dy = pn[1] - pb[1];
  const float dz = pn[2] - pb[2];
  float v = dx * dx + dy * dy + dz * dz;
  for (int o = 32; o > 0; o >>= 1) v += __shfl_down(v, o);
  __shared__ float wsum[4];
  if ((t & 63) == 0) wsum[t >> 6] = v;
  __syncthreads();
  if (t == 0) out[b] = (wsum[0] + wsum[1] + wsum[2] + wsum[3]) * (1.0f / L_);
}

extern "C" void kernel_launch(void* const* d_in, const int* in_sizes, int n_in,
                              void* d_out, int out_size, void* d_ws, size_t ws_size,
                              hipStream_t stream) {
  const int* aa = (const int*)d_in[0];
  const float* bb = (const float*)d_in[1];
  const float* emb = (const float*)d_in[2];
  const float* conv_w = (const float*)d_in[3];
  const float* conv_b = (const float*)d_in[4];
  const float* t1w = (const float*)d_in[5];
  const float* t1b = (const float*)d_in[6];
  const float* t2w = (const float*)d_in[7];
  const float* t2b = (const float*)d_in[8];
  float* out = (float*)d_out;

  char* ws = (char*)d_ws;
  float* hA = (float*)ws;                          // 8388608 B
  float* hB = (float*)(ws + 8388608);              // 8388608 B
  float* nbb = (float*)(ws + 2 * 8388608);         // 196608 B  (total ~17 MB)

  // embed -> hA (B,E,L)
  k_embed<<<(B_ * E_ * L_ + 255) / 256, 256, 0, stream>>>(aa, emb, hA);

  // 4 conv layers, ping-pong: hA->hB->hA->hB->hA
  for (int i = 0; i < NL_; ++i) {
    const float* src = (i & 1) ? hB : hA;
    float* dst = (i & 1) ? hA : hB;
    k_conv<<<dim3(L_ / 32, B_), 256, 0, stream>>>(src, conv_w + (size_t)i * E_ * E_ * K_,
                                                  conv_b + i * E_, dst);
  }

  // transpose hA (B,E,L) -> hB (B,L,E)  [hB free again after layer 3]
  k_transpose<<<dim3(L_ / 32, E_ / 32, B_), 256, 0, stream>>>(hA, hB);

  // fused pairwise kernel -> nbb
  k_fused<<<B_ * (L_ / 8), 512, 0, stream>>>(hB, bb, t1w, t1b, t2w, t2b, nbb);

  // mse -> out (63)
  k_mse<<<B_ - 1, 256, 0, stream>>>(nbb, bb, out);
}

// Round 2
// 346.789 us; speedup vs baseline: 2.9457x; 2.9457x over previous
//
#include <hip/hip_runtime.h>

#define B_ 64
#define L_ 256
#define E_ 128
#define C_ 16
#define K_ 5
#define NL_ 4
#define STEP_ 0.1f

typedef __bf16 bfh;
typedef __attribute__((ext_vector_type(8))) __bf16 bf16x8;
typedef __attribute__((ext_vector_type(4))) float f32x4;

// ---------------- embedding gather: h0[b,e,l] = emb[aa[b,l], e] ----------------
__global__ void k_embed(const int* __restrict__ aa, const float* __restrict__ emb,
                        float* __restrict__ h0) {
  int idx = blockIdx.x * 256 + threadIdx.x;
  if (idx >= B_ * E_ * L_) return;
  int l = idx & (L_ - 1);
  int e = (idx >> 8) & (E_ - 1);
  int b = idx >> 15;
  h0[idx] = emb[aa[b * L_ + l] * E_ + e];
}

// ---------------- one conv layer: hout = tanh(hin + conv(hin,w) + bias) ----------------
__global__ __launch_bounds__(256) void k_conv(const float* __restrict__ hin,
                                              const float* __restrict__ w,
                                              const float* __restrict__ bias,
                                              float* __restrict__ hout) {
  __shared__ __align__(16) float hs[E_][40];
  const int b = blockIdx.y;
  const int lb = blockIdx.x * 32;
  const int t = threadIdx.x;

  for (int s = t; s < E_ * 36; s += 256) {
    int i = s / 36, xw = s - i * 36;
    int lp = lb + xw - 2;
    hs[i][xw] = (lp >= 0 && lp < L_) ? hin[(b * E_ + i) * L_ + lp] : 0.0f;
  }
  __syncthreads();

  const int o = t >> 1, lh = t & 1;
  const int l0 = lh * 16;
  float acc[16];
#pragma unroll
  for (int j = 0; j < 16; ++j) acc[j] = 0.0f;

  const float* wrow = w + o * (E_ * K_);
  for (int i = 0; i < E_; ++i) {
    const float wv0 = wrow[i * 5 + 0];
    const float wv1 = wrow[i * 5 + 1];
    const float wv2 = wrow[i * 5 + 2];
    const float wv3 = wrow[i * 5 + 3];
    const float wv4 = wrow[i * 5 + 4];
    const float4* hp = reinterpret_cast<const float4*>(&hs[i][l0]);
    float4 q0 = hp[0], q1 = hp[1], q2 = hp[2], q3 = hp[3], q4 = hp[4];
    float hw[20] = {q0.x, q0.y, q0.z, q0.w, q1.x, q1.y, q1.z, q1.w,
                    q2.x, q2.y, q2.z, q2.w, q3.x, q3.y, q3.z, q3.w,
                    q4.x, q4.y, q4.z, q4.w};
#pragma unroll
    for (int j = 0; j < 16; ++j) {
      acc[j] = fmaf(wv0, hw[j], acc[j]);
      acc[j] = fmaf(wv1, hw[j + 1], acc[j]);
      acc[j] = fmaf(wv2, hw[j + 2], acc[j]);
      acc[j] = fmaf(wv3, hw[j + 3], acc[j]);
      acc[j] = fmaf(wv4, hw[j + 4], acc[j]);
    }
  }
  const float bo = bias[o];
#pragma unroll
  for (int j = 0; j < 16; ++j) {
    float res = hs[o][l0 + j + 2];
    hout[(b * E_ + o) * L_ + lb + l0 + j] = tanhf(acc[j] + res + bo);
  }
}

// ---------------- transpose (B,E,L) fp32 -> (B,L,E) bf16 ----------------
__global__ void k_transpose(const float* __restrict__ h, bfh* __restrict__ x) {
  __shared__ float tl[32][33];
  const int b = blockIdx.z;
  const int lt = blockIdx.x * 32;
  const int et = blockIdx.y * 32;
  const int tx = threadIdx.x & 31, ty = threadIdx.x >> 5;
  for (int r = ty; r < 32; r += 8)
    tl[r][tx] = h[(b * E_ + et + r) * L_ + lt + tx];
  __syncthreads();
  for (int r = ty; r < 32; r += 8)
    x[(size_t)(b * L_ + lt + r) * E_ + et + tx] = (bfh)tl[tx][r];
}

// ---------------- convert t1w fp32 -> bf16 ----------------
__global__ void k_prep_t1w(const float* __restrict__ t1w, bfh* __restrict__ t1wb) {
  int i = blockIdx.x * 256 + threadIdx.x;
  if (i < 2048 * 128) t1wb[i] = (bfh)t1w[i];
}

// ---------------- fused MFMA kernel ----------------
// grid = B * 16 (a-tiles of 16), block 512 (8 waves). LDS row stride 272B.
#define X2S 0            // 256 rows x 272B  (x2 tile, rows = a*16+c, cols = e bf16)
#define XDS 69632        // 64 rows  x 272B  (x d-chunk)
#define XAS 87040        // 16 rows  x 272B  (x a-tile)
#define BBS 91392        // 768 f32
#define RED 94464        // 16a x 16c x 4 f32
#define SMEM_SZ 98560
#define RSTR 272

__global__ __launch_bounds__(512, 2) void k_fused2(
    const bfh* __restrict__ xbg,    // (B,L,E) bf16
    const float* __restrict__ bb,   // (B,L,3)
    const bfh* __restrict__ t1wb,   // (2048,128) bf16
    const float* __restrict__ t1b,  // (2048)
    const float* __restrict__ t2w,  // (48,3)
    const float* __restrict__ t2b,  // (48)
    float* __restrict__ nbb)        // (B,L,3)
{
  __shared__ __align__(16) char smem[SMEM_SZ];
  const int t = threadIdx.x;
  const int b = blockIdx.x >> 4;
  const int a0 = (blockIdx.x & 15) << 4;
  const int lane = t & 63;
  const int w = t >> 6;
  const int c16 = lane & 15;
  const int kg = lane >> 4;

  float* bbs = (float*)(smem + BBS);
  if (t < 192) ((float4*)bbs)[t] = ((const float4*)(bb + b * (L_ * 3)))[t];
  if (t < 256) {
    int row = t >> 4, u = t & 15;
    *(bf16x8*)(smem + XAS + row * RSTR + u * 16) =
        *(const bf16x8*)(xbg + (size_t)(b * L_ + a0 + row) * E_ + u * 8);
  }
  __syncthreads();

  // ---- phase 1: x2[a, e, c] tile via MFMA. M=16 a, N=2048 (n=e*16+c), K=128 ----
  {
    bf16x8 afr[4];
#pragma unroll
    for (int kk = 0; kk < 4; ++kk)
      afr[kk] = *(const bf16x8*)(smem + XAS + c16 * RSTR + kk * 64 + kg * 16);
    for (int nt = w * 16; nt < w * 16 + 16; ++nt) {
      const int n0 = nt << 4;
      const bfh* bsrc = t1wb + (size_t)(n0 + c16) * E_;
      f32x4 acc = {0.f, 0.f, 0.f, 0.f};
#pragma unroll
      for (int kk = 0; kk < 4; ++kk) {
        bf16x8 bfr = *(const bf16x8*)(bsrc + kk * 32 + kg * 8);
        acc = __builtin_amdgcn_mfma_f32_16x16x32_bf16(afr[kk], bfr, acc, 0, 0, 0);
      }
      const float bias = t1b[n0 + c16];
      // element (a=kg*4+r, c=c16, e=nt) -> x2s[a*16+c][e]
#pragma unroll
      for (int r = 0; r < 4; ++r) {
        int asub = kg * 4 + r;
        *(bfh*)(smem + X2S + (asub * 16 + c16) * RSTR + nt * 2) = (bfh)(acc[r] + bias);
      }
    }
  }
  __syncthreads();

  // ---- phase 2: scores S[c][d] per a + softmax(C) + pairwise accumulation ----
  // wave w owns a_sub {2w, 2w+1}
  bf16x8 afr2[2][4];
#pragma unroll
  for (int as = 0; as < 2; ++as) {
    int arow = (2 * w + as) * 16 + c16;  // row = a*16 + c, lane supplies row c=c16
#pragma unroll
    for (int kk = 0; kk < 4; ++kk)
      afr2[as][kk] = *(const bf16x8*)(smem + X2S + arow * RSTR + kk * 64 + kg * 16);
  }
  float bax[2][3];
#pragma unroll
  for (int as = 0; as < 2; ++as) {
    int ag = a0 + 2 * w + as;
#pragma unroll
    for (int m = 0; m < 3; ++m) bax[as][m] = bbs[ag * 3 + m];
  }
  float accS[2][4], accX[2][4], accY[2][4], accZ[2][4];
#pragma unroll
  for (int as = 0; as < 2; ++as)
#pragma unroll
    for (int r = 0; r < 4; ++r) {
      accS[as][r] = 0.f; accX[as][r] = 0.f; accY[as][r] = 0.f; accZ[as][r] = 0.f;
    }

  for (int ch = 0; ch < 4; ++ch) {
    __syncthreads();  // previous chunk's reads done
#pragma unroll
    for (int uu = 0; uu < 2; ++uu) {
      int u = t + uu * 512;
      int row = u >> 4, cu = u & 15;
      *(bf16x8*)(smem + XDS + row * RSTR + cu * 16) =
          *(const bf16x8*)(xbg + (size_t)(b * L_ + ch * 64 + row) * E_ + cu * 8);
    }
    __syncthreads();

    for (int dt = 0; dt < 4; ++dt) {
      bf16x8 bfr[4];
#pragma unroll
      for (int kk = 0; kk < 4; ++kk)
        bfr[kk] = *(const bf16x8*)(smem + XDS + (dt * 16 + c16) * RSTR + kk * 64 + kg * 16);
      const int dloc = ch * 64 + dt * 16 + c16;
      const float bdx = bbs[dloc * 3 + 0];
      const float bdy = bbs[dloc * 3 + 1];
      const float bdz = bbs[dloc * 3 + 2];
#pragma unroll
      for (int as = 0; as < 2; ++as) {
        f32x4 acc = {0.f, 0.f, 0.f, 0.f};
#pragma unroll
        for (int kk = 0; kk < 4; ++kk)
          acc = __builtin_amdgcn_mfma_f32_16x16x32_bf16(afr2[as][kk], bfr[kk], acc, 0, 0, 0);
        // lane holds S[c = kg*4+r][d = dloc]; softmax over 16 c = regs + lanes +-16,+-32
        float mx = fmaxf(fmaxf(acc[0], acc[1]), fmaxf(acc[2], acc[3]));
        mx = fmaxf(mx, __shfl_xor(mx, 16));
        mx = fmaxf(mx, __shfl_xor(mx, 32));
        float p[4], s = 0.f;
#pragma unroll
        for (int r = 0; r < 4; ++r) { p[r] = __expf(acc[r] - mx); s += p[r]; }
        s += __shfl_xor(s, 16);
        s += __shfl_xor(s, 32);
        const float inv = __builtin_amdgcn_rcpf(s);
        const float dx = bax[as][0] - bdx;
        const float dy = bax[as][1] - bdy;
        const float dz = bax[as][2] - bdz;
#pragma unroll
        for (int r = 0; r < 4; ++r) {
          const float sm = p[r] * inv;
          accS[as][r] += sm;
          accX[as][r] = fmaf(sm, dx, accX[as][r]);
          accY[as][r] = fmaf(sm, dy, accY[as][r]);
          accZ[as][r] = fmaf(sm, dz, accZ[as][r]);
        }
      }
    }
  }

  // ---- phase 3: reduce over the 16 d-lanes (xor 1,2,4,8), write red ----
  float* red = (float*)(smem + RED);
#pragma unroll
  for (int as = 0; as < 2; ++as)
#pragma unroll
    for (int r = 0; r < 4; ++r) {
      float vx = accX[as][r], vy = accY[as][r], vz = accZ[as][r], vs = accS[as][r];
#pragma unroll
      for (int m = 1; m <= 8; m <<= 1) {
        vx += __shfl_xor(vx, m);
        vy += __shfl_xor(vy, m);
        vz += __shfl_xor(vz, m);
        vs += __shfl_xor(vs, m);
      }
      if (c16 == 0) {
        int a = 2 * w + as, c = kg * 4 + r;
        float* rr = red + (a * 16 + c) * 4;
        rr[0] = vx; rr[1] = vy; rr[2] = vz; rr[3] = vs;
      }
    }
  __syncthreads();

  // ---- phase 4: vd and new_bb ----
  if (t < 48) {
    int a = t / 3, k = t % 3;
    float vd = 0.f;
#pragma unroll
    for (int c = 0; c < C_; ++c) {
      const float* w2 = t2w + (k * C_ + c) * 3;
      const float* rr = red + (a * 16 + c) * 4;
      vd += w2[0] * rr[0] + w2[1] * rr[1] + w2[2] * rr[2] + t2b[k * C_ + c] * rr[3];
    }
    nbb[(size_t)(b * L_ + a0 + a) * 3 + k] = bbs[(a0 + a) * 3 + k] + STEP_ * vd;
  }
}

// ---------------- mse over frames ----------------
__global__ void k_mse(const float* __restrict__ nbb, const float* __restrict__ bb,
                      float* __restrict__ out) {
  const int b = blockIdx.x;
  const int t = threadIdx.x;
  const float* pn = nbb + ((b + 1) * L_ + t) * 3;
  const float* pb = bb + (b * L_ + t) * 3;
  const float dx = pn[0] - pb[0];
  const float dy = pn[1] - pb[1];
  const float dz = pn[2] - pb[2];
  float v = dx * dx + dy * dy + dz * dz;
  for (int o = 32; o > 0; o >>= 1) v += __shfl_down(v, o);
  __shared__ float wsum[4];
  if ((t & 63) == 0) wsum[t >> 6] = v;
  __syncthreads();
  if (t == 0) out[b] = (wsum[0] + wsum[1] + wsum[2] + wsum[3]) * (1.0f / L_);
}

extern "C" void kernel_launch(void* const* d_in, const int* in_sizes, int n_in,
                              void* d_out, int out_size, void* d_ws, size_t ws_size,
                              hipStream_t stream) {
  const int* aa = (const int*)d_in[0];
  const float* bb = (const float*)d_in[1];
  const float* emb = (const float*)d_in[2];
  const float* conv_w = (const float*)d_in[3];
  const float* conv_b = (const float*)d_in[4];
  const float* t1w = (const float*)d_in[5];
  const float* t1b = (const float*)d_in[6];
  const float* t2w = (const float*)d_in[7];
  const float* t2b = (const float*)d_in[8];
  float* out = (float*)d_out;

  char* ws = (char*)d_ws;
  float* hA = (float*)ws;                           // 8 MB (B,E,L) fp32
  float* hB = (float*)(ws + 8388608);               // 8 MB
  bfh* xbg = (bfh*)(ws + 16777216);                 // 4 MB (B,L,E) bf16
  bfh* t1wb = (bfh*)(ws + 20971520);                // 512 KB
  float* nbb = (float*)(ws + 21495808);             // 192 KB

  k_prep_t1w<<<1024, 256, 0, stream>>>(t1w, t1wb);

  k_embed<<<(B_ * E_ * L_ + 255) / 256, 256, 0, stream>>>(aa, emb, hA);

  for (int i = 0; i < NL_; ++i) {
    const float* src = (i & 1) ? hB : hA;
    float* dst = (i & 1) ? hA : hB;
    k_conv<<<dim3(L_ / 32, B_), 256, 0, stream>>>(src, conv_w + (size_t)i * E_ * E_ * K_,
                                                  conv_b + i * E_, dst);
  }

  k_transpose<<<dim3(L_ / 32, E_ / 32, B_), 256, 0, stream>>>(hA, xbg);

  k_fused2<<<B_ * 16, 512, 0, stream>>>(xbg, bb, t1wb, t1b, t2w, t2b, nbb);

  k_mse<<<B_ - 1, 256, 0, stream>>>(nbb, bb, out);
}

// Round 3
// 207.373 us; speedup vs baseline: 4.9261x; 1.6723x over previous
//
#include <hip/hip_runtime.h>

#define B_ 64
#define L_ 256
#define E_ 128
#define C_ 16
#define K_ 5
#define NL_ 4
#define STEP_ 0.1f

typedef __bf16 bfh;
typedef __attribute__((ext_vector_type(8))) __bf16 bf16x8;
typedef __attribute__((ext_vector_type(4))) float f32x4;
typedef __attribute__((ext_vector_type(16))) float f32x16;

// ---------------- embedding gather -> (B,L,E) bf16 ----------------
__global__ void k_embed(const int* __restrict__ aa, const float* __restrict__ emb,
                        bfh* __restrict__ x0) {
  int i4 = blockIdx.x * 256 + threadIdx.x;  // one float4 of emb per thread
  if (i4 >= B_ * L_ * E_ / 4) return;
  int e4 = i4 & 31;
  int l = (i4 >> 5) & (L_ - 1);
  int b = i4 >> 13;
  float4 v = *(const float4*)(emb + (size_t)aa[b * L_ + l] * E_ + e4 * 4);
  union { bfh h[4]; uint2 u; } pk;
  pk.h[0] = (bfh)v.x; pk.h[1] = (bfh)v.y; pk.h[2] = (bfh)v.z; pk.h[3] = (bfh)v.w;
  *(uint2*)(x0 + (size_t)(b * L_ + l) * E_ + e4 * 4) = pk.u;
}

// ---------------- conv weights fp32 (o,i,k) -> bf16 wT[lay][k][o][i] ----------------
__global__ void k_prep_w(const float* __restrict__ w, bfh* __restrict__ wT) {
  int i = blockIdx.x * 256 + threadIdx.x;
  if (i >= NL_ * K_ * E_ * E_) return;
  int ii = i & 127;
  int rest = i >> 7;
  int o = rest & 127;
  int rest2 = rest >> 7;
  int k = rest2 % K_;
  int lay = rest2 / K_;
  wT[i] = (bfh)w[(((size_t)lay * E_ + o) * E_ + ii) * K_ + k];
}

// ---------------- t1w fp32 -> bf16 ----------------
__global__ void k_prep_t1(const float* __restrict__ t1w, bfh* __restrict__ t1wb) {
  int i = blockIdx.x * 256 + threadIdx.x;
  if (i < 2048 * 128) t1wb[i] = (bfh)t1w[i];
}

// ---------------- conv layer via MFMA: x (B,L,E) bf16 -> (B,L,E) bf16 ----------------
// grid (L/32, B), 512 threads (8 waves): wave = (msub 0..1) x (nq 0..3)
__global__ __launch_bounds__(512, 4) void k_conv(const bfh* __restrict__ xin,
                                                 const bfh* __restrict__ wT,  // layer base
                                                 const float* __restrict__ bias,
                                                 bfh* __restrict__ xout) {
  __shared__ __align__(16) char hs[36 * 256];
  const int b = blockIdx.y;
  const int lb = blockIdx.x * 32;
  const int t = threadIdx.x;

  // stage rows lb-2 .. lb+33 (swizzled 16B chunks: chunk ^= row&7)
  for (int s = t; s < 36 * 16; s += 512) {
    int row = s >> 4, ch = s & 15;
    int lp = lb + row - 2;
    uint4 z = {0, 0, 0, 0};
    uint4 v = (lp >= 0 && lp < L_)
                  ? *(const uint4*)(xin + ((size_t)b * L_ + lp) * E_ + ch * 8)
                  : z;
    *(uint4*)(hs + row * 256 + ((ch ^ (row & 7)) << 4)) = v;
  }
  __syncthreads();

  const int wv = t >> 6, lane = t & 63;
  const int c16 = lane & 15, kg = lane >> 4;
  const int msub = wv & 1;
  const int nq = wv >> 1;

  bf16x8 af[K_][4];
#pragma unroll
  for (int k = 0; k < K_; ++k)
#pragma unroll
    for (int kk = 0; kk < 4; ++kk) {
      int row = msub * 16 + c16 + k;
      int ch = (kk * 4 + kg) ^ (row & 7);
      af[k][kk] = *(const bf16x8*)(hs + row * 256 + ch * 16);
    }

#pragma unroll
  for (int ntl = 0; ntl < 2; ++ntl) {
    const int n0 = nq * 32 + ntl * 16;
    f32x4 acc = {0.f, 0.f, 0.f, 0.f};
#pragma unroll
    for (int k = 0; k < K_; ++k) {
      const bfh* bp = wT + ((size_t)(k * E_ + n0 + c16)) * E_ + kg * 8;
#pragma unroll
      for (int kk = 0; kk < 4; ++kk)
        acc = __builtin_amdgcn_mfma_f32_16x16x32_bf16(af[k][kk],
                                                      *(const bf16x8*)(bp + kk * 32),
                                                      acc, 0, 0, 0);
    }
    const int o = n0 + c16;
    const float bo = bias[o];
#pragma unroll
    for (int r = 0; r < 4; ++r) {
      int lrow = msub * 16 + kg * 4 + r;
      int srow = lrow + 2;
      float res = (float)*(const bfh*)(hs + srow * 256 +
                                       (((o >> 3) ^ (srow & 7)) << 4) + (o & 7) * 2);
      float v = acc[r] + res + bo;
      float ex = __expf(2.f * v);
      float th = 1.f - 2.f / (ex + 1.f);
      xout[((size_t)b * L_ + lb + lrow) * E_ + o] = (bfh)th;
    }
  }
}

// ---------------- fused MFMA kernel (32x32x16 scores, in-lane softmax) ----------------
#define X2S 0            // 256 rows x 256B, swizzled; rows = apair*32 + m(a_lsb,c)
#define XDS 65536        // 64 rows x 256B, swizzled (aliased as x a-tile in phase 1)
#define BBS 81920        // 768 f32
#define RED 84992        // 16a x 16c x 4m f32
#define SMEM_SZ 89088

__global__ __launch_bounds__(512, 2) void k_fused2(
    const bfh* __restrict__ xbg,    // (B,L,E) bf16
    const float* __restrict__ bb,   // (B,L,3)
    const bfh* __restrict__ t1wb,   // (2048,128) bf16
    const float* __restrict__ t1b,  // (2048)
    const float* __restrict__ t2w,  // (48,3)
    const float* __restrict__ t2b,  // (48)
    float* __restrict__ nbb)        // (B,L,3)
{
  __shared__ __align__(16) char smem[SMEM_SZ];
  const int t = threadIdx.x;
  const int b = blockIdx.x >> 4;
  const int a0 = (blockIdx.x & 15) << 4;
  const int lane = t & 63;
  const int wv = t >> 6;        // 0..7 = a-pair
  const int c16 = lane & 15;
  const int kg = lane >> 4;
  const int l31 = lane & 31;
  const int hi = lane >> 5;

  float* bbs = (float*)(smem + BBS);
  if (t < 192) ((float4*)bbs)[t] = ((const float4*)(bb + b * (L_ * 3)))[t];
  // stage x a-tile (16 rows) into XDS region, swizzled
  if (t < 256) {
    int row = t >> 4, ch = t & 15;
    uint4 v = *(const uint4*)(xbg + ((size_t)b * L_ + a0 + row) * E_ + ch * 8);
    *(uint4*)(smem + XDS + row * 256 + ((ch ^ (row & 7)) << 4)) = v;
  }
  __syncthreads();

  // ---- phase 1: x2 tile via 16x16x32. M=16 a, n-tile nt = e, cols = c ----
  {
    bf16x8 a1[4];
#pragma unroll
    for (int kk = 0; kk < 4; ++kk)
      a1[kk] = *(const bf16x8*)(smem + XDS + c16 * 256 +
                                (((kk * 4 + kg) ^ (c16 & 7)) << 4));
    for (int nt = wv * 16; nt < wv * 16 + 16; ++nt) {
      f32x4 acc = {0.f, 0.f, 0.f, 0.f};
      const bfh* bsrc = t1wb + (size_t)(nt * 16 + c16) * E_ + kg * 8;
#pragma unroll
      for (int kk = 0; kk < 4; ++kk)
        acc = __builtin_amdgcn_mfma_f32_16x16x32_bf16(a1[kk],
                                                      *(const bf16x8*)(bsrc + kk * 32),
                                                      acc, 0, 0, 0);
      const float bias = t1b[nt * 16 + c16];
#pragma unroll
      for (int r = 0; r < 4; ++r) {
        int a = kg * 4 + r;
        int row = (a >> 1) * 32 + ((c16 & 3) | ((a & 1) << 2) | ((c16 >> 2) << 3));
        *(bfh*)(smem + X2S + row * 256 + (((nt >> 3) ^ (row & 7)) << 4) + (nt & 7) * 2) =
            (bfh)(acc[r] + bias);
      }
    }
  }
  __syncthreads();

  // ---- phase 2: scores via 32x32x16 (M = 2a x 16c, N = 32 d), in-lane softmax ----
  bf16x8 afr[8];
#pragma unroll
  for (int kk = 0; kk < 8; ++kk) {
    int row = wv * 32 + l31;
    afr[kk] = *(const bf16x8*)(smem + X2S + row * 256 + (((kk * 2 + hi) ^ (l31 & 7)) << 4));
  }
  const int aglob = a0 + 2 * wv + hi;
  const float bax0 = bbs[aglob * 3 + 0];
  const float bax1 = bbs[aglob * 3 + 1];
  const float bax2 = bbs[aglob * 3 + 2];

  float accX[16], accY[16], accZ[16], accS[16];
#pragma unroll
  for (int q = 0; q < 16; ++q) { accX[q] = 0.f; accY[q] = 0.f; accZ[q] = 0.f; accS[q] = 0.f; }

  for (int ch = 0; ch < 4; ++ch) {
    __syncthreads();
    for (int s = t; s < 1024; s += 512) {
      int row = s >> 4, cc = s & 15;
      uint4 v = *(const uint4*)(xbg + ((size_t)b * L_ + ch * 64 + row) * E_ + cc * 8);
      *(uint4*)(smem + XDS + row * 256 + ((cc ^ (row & 7)) << 4)) = v;
    }
    __syncthreads();
#pragma unroll
    for (int dt2 = 0; dt2 < 2; ++dt2) {
      f32x16 acc;
#pragma unroll
      for (int q = 0; q < 16; ++q) acc[q] = 0.f;
#pragma unroll
      for (int kk = 0; kk < 8; ++kk) {
        int row = dt2 * 32 + l31;
        bf16x8 bfr = *(const bf16x8*)(smem + XDS + row * 256 +
                                      (((kk * 2 + hi) ^ (l31 & 7)) << 4));
        acc = __builtin_amdgcn_mfma_f32_32x32x16_bf16(afr[kk], bfr, acc, 0, 0, 0);
      }
      const int d = ch * 64 + dt2 * 32 + l31;
      const float dx = bax0 - bbs[d * 3 + 0];
      const float dy = bax1 - bbs[d * 3 + 1];
      const float dz = bax2 - bbs[d * 3 + 2];
      float mx = acc[0];
#pragma unroll
      for (int q = 1; q < 16; ++q) mx = fmaxf(mx, acc[q]);
      float p[16], S = 0.f;
#pragma unroll
      for (int q = 0; q < 16; ++q) { p[q] = __expf(acc[q] - mx); S += p[q]; }
      const float inv = __builtin_amdgcn_rcpf(S);
#pragma unroll
      for (int q = 0; q < 16; ++q) {
        const float u = p[q] * inv;
        accS[q] += u;
        accX[q] = fmaf(u, dx, accX[q]);
        accY[q] = fmaf(u, dy, accY[q]);
        accZ[q] = fmaf(u, dz, accZ[q]);
      }
    }
  }

  // ---- phase 3: reduce 32 d-lanes via LDS transpose (2 passes of 8 c), X2S is dead ----
  float* scr = (float*)smem;
  float* red = (float*)(smem + RED);
#pragma unroll
  for (int pass = 0; pass < 2; ++pass) {
    __syncthreads();
#pragma unroll
    for (int c2 = 0; c2 < 8; ++c2) {
      int c = pass * 8 + c2;
      int base = ((wv * 2 + hi) * 8 + c2) * 4;
      scr[(base + 0) * 32 + l31] = accX[c];
      scr[(base + 1) * 32 + l31] = accY[c];
      scr[(base + 2) * 32 + l31] = accZ[c];
      scr[(base + 3) * 32 + l31] = accS[c];
    }
    __syncthreads();
    {
      float v = 0.f;
#pragma unroll
      for (int j = 0; j < 32; ++j) v += scr[t * 32 + ((j + t) & 31)];
      int m = t & 3, c2 = (t >> 2) & 7, hh = (t >> 5) & 1, wp = t >> 6;
      red[((wp * 2 + hh) * 16 + pass * 8 + c2) * 4 + m] = v;
    }
  }
  __syncthreads();

  // ---- phase 4: vd and new_bb ----
  if (t < 48) {
    int a = t / 3, k = t % 3;
    float vd = 0.f;
#pragma unroll
    for (int c = 0; c < C_; ++c) {
      const float* w2 = t2w + (k * C_ + c) * 3;
      const float* rr = red + (a * 16 + c) * 4;
      vd += w2[0] * rr[0] + w2[1] * rr[1] + w2[2] * rr[2] + t2b[k * C_ + c] * rr[3];
    }
    nbb[(size_t)(b * L_ + a0 + a) * 3 + k] = bbs[(a0 + a) * 3 + k] + STEP_ * vd;
  }
}

// ---------------- mse over frames ----------------
__global__ void k_mse(const float* __restrict__ nbb, const float* __restrict__ bb,
                      float* __restrict__ out) {
  const int b = blockIdx.x;
  const int t = threadIdx.x;
  const float* pn = nbb + ((b + 1) * L_ + t) * 3;
  const float* pb = bb + (b * L_ + t) * 3;
  const float dx = pn[0] - pb[0];
  const float dy = pn[1] - pb[1];
  const float dz = pn[2] - pb[2];
  float v = dx * dx + dy * dy + dz * dz;
  for (int o = 32; o > 0; o >>= 1) v += __shfl_down(v, o);
  __shared__ float wsum[4];
  if ((t & 63) == 0) wsum[t >> 6] = v;
  __syncthreads();
  if (t == 0) out[b] = (wsum[0] + wsum[1] + wsum[2] + wsum[3]) * (1.0f / L_);
}

extern "C" void kernel_launch(void* const* d_in, const int* in_sizes, int n_in,
                              void* d_out, int out_size, void* d_ws, size_t ws_size,
                              hipStream_t stream) {
  const int* aa = (const int*)d_in[0];
  const float* bb = (const float*)d_in[1];
  const float* emb = (const float*)d_in[2];
  const float* conv_w = (const float*)d_in[3];
  const float* conv_b = (const float*)d_in[4];
  const float* t1w = (const float*)d_in[5];
  const float* t1b = (const float*)d_in[6];
  const float* t2w = (const float*)d_in[7];
  const float* t2b = (const float*)d_in[8];
  float* out = (float*)d_out;

  char* ws = (char*)d_ws;
  bfh* xA = (bfh*)ws;                         // 4 MB (B,L,E) bf16
  bfh* xB = (bfh*)(ws + 4194304);             // 4 MB
  bfh* t1wb = (bfh*)(ws + 8388608);           // 512 KB
  bfh* wT = (bfh*)(ws + 8912896);             // 640 KB
  float* nbb = (float*)(ws + 9568256);        // 192 KB

  k_prep_t1<<<1024, 256, 0, stream>>>(t1w, t1wb);
  k_prep_w<<<(NL_ * K_ * E_ * E_ + 255) / 256, 256, 0, stream>>>(conv_w, wT);
  k_embed<<<B_ * L_ * E_ / 4 / 256, 256, 0, stream>>>(aa, emb, xA);

  for (int i = 0; i < NL_; ++i) {
    const bfh* src = (i & 1) ? xB : xA;
    bfh* dst = (i & 1) ? xA : xB;
    k_conv<<<dim3(L_ / 32, B_), 512, 0, stream>>>(src, wT + (size_t)i * K_ * E_ * E_,
                                                  conv_b + i * E_, dst);
  }
  // after 4 layers result is in xA

  k_fused2<<<B_ * 16, 512, 0, stream>>>(xA, bb, t1wb, t1b, t2w, t2b, nbb);

  k_mse<<<B_ - 1, 256, 0, stream>>>(nbb, bb, out);
}